// Round 6
// baseline (403.932 us; speedup 1.0000x reference)
//
#include <hip/hip_runtime.h>
#include <hip/hip_bf16.h>

#define NN 8192
#define FIN 128
#define FOUT 64
#define JCH 512      // columns per chunk (2 KB/row contiguous burst)
#define NCH 16       // chunks (NCH*JCH == NN)
#define PSTR 520     // Pbuf row stride in shorts (512 + 8; 1040 B, 16B-aligned rows)

typedef __attribute__((ext_vector_type(8))) short short8;
typedef __attribute__((ext_vector_type(4))) short short4v;
typedef __attribute__((ext_vector_type(4))) float floatx4;
typedef __attribute__((ext_vector_type(4))) int intx4;

__device__ __forceinline__ short f2bf_rne(float x) {
  union { float f; unsigned u; } c; c.f = x;
  unsigned r = c.u + 0x7fffu + ((c.u >> 16) & 1u);
  return (short)(r >> 16);
}
__device__ __forceinline__ float bf2f(short b) {
  union { unsigned u; float f; } c; c.u = ((unsigned)(unsigned short)b) << 16;
  return c.f;
}

// Kernel A: h = x @ W^T (fp32), s_src/s_dst, and Hb = bf16 h pre-swizzled into
// MFMA-B-fragment order: Hb[((c*4 + ftile)*64 + quad*16 + fi)*8 + v] = h[c*32+quad*8+v][ftile*16+fi]
__global__ __launch_bounds__(256) void prep_kernel(
    const float* __restrict__ x, const float* __restrict__ W,
    const float* __restrict__ att_w,
    short* __restrict__ Hb, float* __restrict__ s_src, float* __restrict__ s_dst) {
  __shared__ float xs[16 * FIN];  // 8 KB: 16 rows of x
  const int t = threadIdx.x;
  const int bid = blockIdx.x;
#pragma unroll
  for (int i = 0; i < 8; ++i)
    xs[t + i * 256] = x[(size_t)bid * (16 * FIN) + t + i * 256];
  __syncthreads();
  const int w = t >> 6;     // wave handles rows w*4 .. w*4+3
  const int f = t & 63;     // lane == output feature
  const float4* Wf4 = (const float4*)(W + f * FIN);
  const float4* xr0 = (const float4*)(xs + (w * 4 + 0) * FIN);
  const float4* xr1 = (const float4*)(xs + (w * 4 + 1) * FIN);
  const float4* xr2 = (const float4*)(xs + (w * 4 + 2) * FIN);
  const float4* xr3 = (const float4*)(xs + (w * 4 + 3) * FIN);
  float h0 = 0.f, h1 = 0.f, h2 = 0.f, h3 = 0.f;
#pragma unroll
  for (int k = 0; k < FIN / 4; ++k) {
    float4 wv = Wf4[k];
    float4 v0 = xr0[k], v1 = xr1[k], v2 = xr2[k], v3 = xr3[k];
    h0 = fmaf(v0.x, wv.x, h0); h0 = fmaf(v0.y, wv.y, h0);
    h0 = fmaf(v0.z, wv.z, h0); h0 = fmaf(v0.w, wv.w, h0);
    h1 = fmaf(v1.x, wv.x, h1); h1 = fmaf(v1.y, wv.y, h1);
    h1 = fmaf(v1.z, wv.z, h1); h1 = fmaf(v1.w, wv.w, h1);
    h2 = fmaf(v2.x, wv.x, h2); h2 = fmaf(v2.y, wv.y, h2);
    h2 = fmaf(v2.z, wv.z, h2); h2 = fmaf(v2.w, wv.w, h2);
    h3 = fmaf(v3.x, wv.x, h3); h3 = fmaf(v3.y, wv.y, h3);
    h3 = fmaf(v3.z, wv.z, h3); h3 = fmaf(v3.w, wv.w, h3);
  }
  const float asrc = att_w[f];
  const float adst = att_w[FOUT + f];
  float hv[4] = {h0, h1, h2, h3};
#pragma unroll
  for (int g = 0; g < 4; ++g) {
    float v1 = hv[g] * asrc;
    float v2 = hv[g] * adst;
#pragma unroll
    for (int off = 32; off > 0; off >>= 1) {
      v1 += __shfl_xor(v1, off, 64);
      v2 += __shfl_xor(v2, off, 64);
    }
    const int r = bid * 16 + w * 4 + g;
    if (f == 0) { s_src[r] = v1; s_dst[r] = v2; }
    const int c = r >> 5;
    const int quad = (r >> 3) & 3;
    const int vv = r & 7;
    const int tile = f >> 4;
    const int fi = f & 15;
    Hb[(((c * 4 + tile) * 64) + quad * 16 + fi) * 8 + vv] = f2bf_rne(hv[g]);
  }
}

// p for 4 consecutive columns of one row; returns packed bf16, accumulates denominator
__device__ __forceinline__ short4v pcalc(float ssrc, intx4 a, float4 s, float& dsum) {
  float sv[4] = {s.x, s.y, s.z, s.w};
  int av[4] = {a.x, a.y, a.z, a.w};
  short4v r;
#pragma unroll
  for (int v = 0; v < 4; ++v) {
    float tt = ssrc + sv[v];
    float e = fmaxf(tt, 0.f) + 0.01f * fminf(tt, 0.f);  // leaky_relu
    float p = __expf(e);
    p = (av[v] > 0) ? p : 0.f;
    short bb = f2bf_rne(p);
    r[v] = bb;
    dsum += bf2f(bb);  // denominator from bf16-rounded weight: exact normalization
  }
  return r;
}

// gat v3: block = 16 rows, 8 waves. Wave w owns rows 2w,2w+1; per chunk it
// reads 2 KB CONTIGUOUS per row (2 back-to-back 1 KB wave-loads) to maximize
// DRAM row-buffer locality across the 8192 concurrent row-streams. Single
// Pbuf, 2 barriers/iter. vmem issue order per iter: Hb(c+1) BEFORE adj(c+2),
// so MFMA's Hb wait is vmcnt(4) and never drains the HBM adj stream.
__global__ __launch_bounds__(512, 4) void gat_kernel(
    const int* __restrict__ adj, const short8* __restrict__ Hb,
    const float* __restrict__ s_src, const float* __restrict__ s_dst,
    float* __restrict__ out) {
  __shared__ short Pbuf[16][PSTR];    // 16.3 KB: p-values for one chunk
  __shared__ float part[8][16][64];   // 32 KB: per-wave partial numerators
  __shared__ float dden[16];          // full row denominators
  const int tid = threadIdx.x;
  const int w = tid >> 6;
  const int lane = tid & 63;
  const int m = lane & 15;
  const int quad = lane >> 4;
  const int bid = blockIdx.x;
  const int i0 = bid * 16;
  const int rA = 2 * w, rB = 2 * w + 1;
  const float ssA = s_src[i0 + rA];
  const float ssB = s_src[i0 + rB];
  const int* adjA = adj + (size_t)(i0 + rA) * NN + lane * 4;
  const int* adjB = adj + (size_t)(i0 + rB) * NN + lane * 4;
  const float* sdp = s_dst + lane * 4;

  floatx4 acc0 = {0.f, 0.f, 0.f, 0.f};
  floatx4 acc1 = acc0, acc2 = acc0, acc3 = acc0;
  float dsA = 0.f, dsB = 0.f;

  // ---- prologue ----
  int cc = bid & (NCH - 1);
  intx4 aA0 = __builtin_nontemporal_load((const intx4*)(adjA + cc * JCH));
  intx4 aA1 = __builtin_nontemporal_load((const intx4*)(adjA + cc * JCH + 256));
  intx4 aB0 = __builtin_nontemporal_load((const intx4*)(adjB + cc * JCH));
  intx4 aB1 = __builtin_nontemporal_load((const intx4*)(adjB + cc * JCH + 256));
  float4 sv0 = *(const float4*)(sdp + cc * JCH);
  float4 sv1 = *(const float4*)(sdp + cc * JCH + 256);
  *(short4v*)&Pbuf[rA][lane * 4]       = pcalc(ssA, aA0, sv0, dsA);
  *(short4v*)&Pbuf[rA][256 + lane * 4] = pcalc(ssA, aA1, sv1, dsA);
  *(short4v*)&Pbuf[rB][lane * 4]       = pcalc(ssB, aB0, sv0, dsB);
  *(short4v*)&Pbuf[rB][256 + lane * 4] = pcalc(ssB, aB1, sv1, dsB);
  // Hb(chunk 0): issued BEFORE adj(chunk 1)
  short8 h00, h01, h02, h03, h10, h11, h12, h13;
  {
    const short8* hp = Hb + (size_t)((cc * 16 + w * 2) * 4) * 64 + lane;
    h00 = hp[0];   h01 = hp[64];  h02 = hp[128]; h03 = hp[192];
    h10 = hp[256]; h11 = hp[320]; h12 = hp[384]; h13 = hp[448];
  }
  {
    const int c1 = (bid + 1) & (NCH - 1);
    aA0 = __builtin_nontemporal_load((const intx4*)(adjA + c1 * JCH));
    aA1 = __builtin_nontemporal_load((const intx4*)(adjA + c1 * JCH + 256));
    aB0 = __builtin_nontemporal_load((const intx4*)(adjB + c1 * JCH));
    aB1 = __builtin_nontemporal_load((const intx4*)(adjB + c1 * JCH + 256));
  }
  __syncthreads();

  for (int c = 0; c < NCH; ++c) {
    // ---- consume chunk c: A-frags from Pbuf, MFMA (waits Hb only) ----
    short8 af0 = *(const short8*)&Pbuf[m][w * 64 + quad * 8];
    short8 af1 = *(const short8*)&Pbuf[m][w * 64 + 32 + quad * 8];
    acc0 = __builtin_amdgcn_mfma_f32_16x16x32_bf16(af0, h00, acc0, 0, 0, 0);
    acc1 = __builtin_amdgcn_mfma_f32_16x16x32_bf16(af0, h01, acc1, 0, 0, 0);
    acc2 = __builtin_amdgcn_mfma_f32_16x16x32_bf16(af0, h02, acc2, 0, 0, 0);
    acc3 = __builtin_amdgcn_mfma_f32_16x16x32_bf16(af0, h03, acc3, 0, 0, 0);
    acc0 = __builtin_amdgcn_mfma_f32_16x16x32_bf16(af1, h10, acc0, 0, 0, 0);
    acc1 = __builtin_amdgcn_mfma_f32_16x16x32_bf16(af1, h11, acc1, 0, 0, 0);
    acc2 = __builtin_amdgcn_mfma_f32_16x16x32_bf16(af1, h12, acc2, 0, 0, 0);
    acc3 = __builtin_amdgcn_mfma_f32_16x16x32_bf16(af1, h13, acc3, 0, 0, 0);
    __syncthreads();  // all waves done reading Pbuf
    if (c + 1 < NCH) {
      const int c1 = (c + 1 + bid) & (NCH - 1);
      // ---- produce chunk c+1 (consumes adj regs loaded in iter c-1) ----
      float4 s0 = *(const float4*)(sdp + c1 * JCH);
      float4 s1 = *(const float4*)(sdp + c1 * JCH + 256);
      *(short4v*)&Pbuf[rA][lane * 4]       = pcalc(ssA, aA0, s0, dsA);
      *(short4v*)&Pbuf[rA][256 + lane * 4] = pcalc(ssA, aA1, s1, dsA);
      *(short4v*)&Pbuf[rB][lane * 4]       = pcalc(ssB, aB0, s0, dsB);
      *(short4v*)&Pbuf[rB][256 + lane * 4] = pcalc(ssB, aB1, s1, dsB);
      // Hb(c+1): issue BEFORE adj(c+2) so consume waits vmcnt(4), not 0
      const short8* hp = Hb + (size_t)((c1 * 16 + w * 2) * 4) * 64 + lane;
      h00 = hp[0];   h01 = hp[64];  h02 = hp[128]; h03 = hp[192];
      h10 = hp[256]; h11 = hp[320]; h12 = hp[384]; h13 = hp[448];
      if (c + 2 < NCH) {
        const int c2 = (c + 2 + bid) & (NCH - 1);
        aA0 = __builtin_nontemporal_load((const intx4*)(adjA + c2 * JCH));
        aA1 = __builtin_nontemporal_load((const intx4*)(adjA + c2 * JCH + 256));
        aB0 = __builtin_nontemporal_load((const intx4*)(adjB + c2 * JCH));
        aB1 = __builtin_nontemporal_load((const intx4*)(adjB + c2 * JCH + 256));
      }
    }
    __syncthreads();  // Pbuf(c+1) visible
  }

  // full row denominators: wave w produced ALL of rows 2w,2w+1
#pragma unroll
  for (int off = 1; off < 64; off <<= 1) {
    dsA += __shfl_xor(dsA, off, 64);
    dsB += __shfl_xor(dsB, off, 64);
  }
  if (lane == 0) { dden[rA] = dsA; dden[rB] = dsB; }

  // C/D layout: col = lane&15 (feature within tile), row = quad*4 + reg
  const int col = lane & 15;
#pragma unroll
  for (int rg = 0; rg < 4; ++rg) {
    part[w][quad * 4 + rg][col]      = acc0[rg];
    part[w][quad * 4 + rg][16 + col] = acc1[rg];
    part[w][quad * 4 + rg][32 + col] = acc2[rg];
    part[w][quad * 4 + rg][48 + col] = acc3[rg];
  }
  __syncthreads();

  // epilogue: sum 8 wave-partials (disjoint j), normalize, ELU, coalesced store
  for (int idx = tid; idx < 16 * 64; idx += 512) {
    int mr = idx >> 6, fc = idx & 63;
    float num = 0.f;
#pragma unroll
    for (int ww = 0; ww < 8; ++ww) num += part[ww][mr][fc];
    float o = num / dden[mr];
    o = (o > 0.f) ? o : (__expf(o) - 1.f);
    out[(size_t)(i0 + mr) * FOUT + fc] = o;
  }
}

extern "C" void kernel_launch(void* const* d_in, const int* in_sizes, int n_in,
                              void* d_out, int out_size, void* d_ws, size_t ws_size,
                              hipStream_t stream) {
  const float* x     = (const float*)d_in[0];
  const int*   adj   = (const int*)d_in[1];
  const float* W     = (const float*)d_in[2];
  const float* att_w = (const float*)d_in[3];
  float* out = (float*)d_out;
  char* ws = (char*)d_ws;
  short* Hb = (short*)ws;                                   // 1 MB bf16 swizzled h
  float* s_src = (float*)(ws + (size_t)NN * FOUT * sizeof(short));
  float* s_dst = s_src + NN;
  prep_kernel<<<NN / 16, 256, 0, stream>>>(x, W, att_w, Hb, s_src, s_dst);
  gat_kernel<<<NN / 16, 512, 0, stream>>>(adj, (const short8*)Hb, s_src, s_dst, out);
}